// Round 1
// baseline (352.131 us; speedup 1.0000x reference)
//
#include <hip/hip_runtime.h>
#include <math.h>

// Problem constants (from reference)
#define ANGN 7
#define NV   49          // ANG*ANG
#define CTR  24          // N//2
#define Himg 256
#define Wimg 256
#define NB   4
#define CROPV 8
#define RW   240         // cropped width/height
#define RWH  (RW*RW)     // 57600 pixels per batch
#define NPIX (NB*RWH)    // 230400 cropped pixels total

// ---------------------------------------------------------------------------
// Kernel A: edge-aware smoothness (grad_loss) partial sums -> acc[1], acc[2]
// ---------------------------------------------------------------------------
__global__ __launch_bounds__(256) void grad_kernel(
    const float* __restrict__ pred, const float* __restrict__ x,
    double* __restrict__ acc)
{
    int eid = blockIdx.x * 256 + threadIdx.x;          // 0..230399 (exact grid)
    int b   = eid / RWH;
    int rem = eid - b * RWH;
    int ry  = rem / RW;
    int yy  = CROPV + ry;
    int xx  = CROPV + (rem - ry * RW);

    // center view image: x[b][3][3][yy][xx][c]
    const float* I  = x + (((b * 7 + 3) * 7 + 3) * Himg * Wimg) * 3;
    const float* pr = pred + b * Himg * Wimg;
    int pidx = yy * Wimg + xx;
    const float* q = I + pidx * 3;
    float a0 = q[0], a1 = q[1], a2 = q[2];

    float lx = 0.0f, ly = 0.0f;
    if (xx <= 246) {  // gx cols cropped to [8,247) of length-255 axis
        float g0 = fabsf(q[3] - a0), g1 = fabsf(q[4] - a1), g2 = fabsf(q[5] - a2);
        float wx = expf(-150.0f * ((g0 + g1 + g2) * (1.0f / 3.0f)));
        lx = wx * fabsf(pr[pidx + 1] - pr[pidx]);
    }
    if (yy <= 246) {  // gy rows cropped to [8,247) of length-255 axis
        const float* r = q + Wimg * 3;
        float g0 = fabsf(r[0] - a0), g1 = fabsf(r[1] - a1), g2 = fabsf(r[2] - a2);
        float wy = expf(-150.0f * ((g0 + g1 + g2) * (1.0f / 3.0f)));
        ly = wy * fabsf(pr[pidx + Wimg] - pr[pidx]);
    }

    // block reduce (wave64 shuffle + LDS across 4 waves)
    #pragma unroll
    for (int off = 32; off > 0; off >>= 1) {
        lx += __shfl_down(lx, off);
        ly += __shfl_down(ly, off);
    }
    __shared__ float sred[8];
    int lane = threadIdx.x & 63, wid = threadIdx.x >> 6;
    if (lane == 0) { sred[wid] = lx; sred[4 + wid] = ly; }
    __syncthreads();
    if (threadIdx.x == 0) {
        atomicAdd(acc + 1, (double)(sred[0] + sred[1] + sred[2] + sred[3]));
        atomicAdd(acc + 2, (double)(sred[4] + sred[5] + sred[6] + sred[7]));
    }
}

// ---------------------------------------------------------------------------
// Kernel B: warp-all + color_loss + angular gauss + stable-rank tail sum
// 64 pixels per block, 4 threads per pixel (sub = tid>>6 handles n = sub+4i)
// ---------------------------------------------------------------------------
__global__ __launch_bounds__(256) void color_kernel(
    const float* __restrict__ pred, const float* __restrict__ x,
    const float* __restrict__ y, const int* __restrict__ epoch_p,
    double* __restrict__ acc)
{
    __shared__ float s_cl[64 * NV];
    __shared__ float s_g [64 * NV];
    __shared__ float sred[4];

    const int tid = threadIdx.x;
    const int pix = tid & 63;
    const int sub = tid >> 6;

    int pid = blockIdx.x * 64 + pix;                   // 0..230399 (exact grid)
    int b   = pid / RWH;
    int rem = pid - b * RWH;
    int ry  = rem / RW;
    int yy  = CROPV + ry;
    int xx  = CROPV + (rem - ry * RW);

    int pidx = (b * Himg + yy) * Wimg + xx;
    float p = pred[pidx];

    // center view pixel (u=v=3)
    const float* cbase = x + ((((b * 7 + 3) * 7 + 3) * Himg + yy) * Wimg + xx) * 3;
    float c0 = cbase[0], c1 = cbase[1], c2 = cbase[2];

    float* mycl = s_cl + pix * NV;
    float* myg  = s_g  + pix * NV;

    // ---- stage 1: bilinear warp + per-view color loss ----
    for (int n = sub; n < NV; n += 4) {
        int u = n / 7;
        int v = n - u * 7;
        float du = (float)(u - 3), dv = (float)(v - 3);
        float cy = fminf(fmaxf((float)yy + p * du, 0.0f), 255.0f);
        float cx = fminf(fmaxf((float)xx + p * dv, 0.0f), 255.0f);
        float y0f = floorf(cy), x0f = floorf(cx);
        float ty = cy - y0f,   tx = cx - x0f;
        int iy0 = (int)y0f,    ix0 = (int)x0f;
        int iy1 = min(iy0 + 1, 255), ix1 = min(ix0 + 1, 255);

        const float* vb  = x + (((b * 7 + u) * 7 + v) * Himg * Wimg) * 3;
        const float* r0  = vb + iy0 * (Wimg * 3);
        const float* r1  = vb + iy1 * (Wimg * 3);
        const float* p00 = r0 + ix0 * 3;
        const float* p01 = r0 + ix1 * 3;
        const float* p10 = r1 + ix0 * 3;
        const float* p11 = r1 + ix1 * 3;

        float w00 = (1.0f - ty) * (1.0f - tx);
        float w01 = (1.0f - ty) * tx;
        float w10 = ty * (1.0f - tx);
        float w11 = ty * tx;

        float o0 = p00[0] * w00 + p01[0] * w01 + p10[0] * w10 + p11[0] * w11;
        float o1 = p00[1] * w00 + p01[1] * w01 + p10[1] * w10 + p11[1] * w11;
        float o2 = p00[2] * w00 + p01[2] * w01 + p10[2] * w10 + p11[2] * w11;

        mycl[n] = (fabsf(o0 - c0) + fabsf(o1 - c1) + fabsf(o2 - c2)) * (1.0f / 3.0f);
    }
    __syncthreads();

    int epoch = *epoch_p;

    // ---- stage 2: 3x3 gaussian over angular grid (edge padded) ----
    if (epoch > 0) {
        const float gw[9] = {0.0751f, 0.1238f, 0.0751f,
                             0.1238f, 0.2042f, 0.1238f,
                             0.0751f, 0.1238f, 0.0751f};
        for (int n = sub; n < NV; n += 4) {
            int u = n / 7;
            int v = n - u * 7;
            float s = 0.0f;
            #pragma unroll
            for (int i = 0; i < 3; i++) {
                int uu = min(max(u + i - 1, 0), 6);
                #pragma unroll
                for (int j = 0; j < 3; j++) {
                    int vv = min(max(v + j - 1, 0), 6);
                    s += gw[i * 3 + j] * mycl[uu * 7 + vv];
                }
            }
            myg[n] = s;
        }
    }
    __syncthreads();

    // ---- stage 3: stable descending rank by key, tail sum over rank > y ----
    const float* key = (epoch > 0) ? myg : mycl;
    float yval = y[pidx];

    float gn[13];
    int   cnt[13];
    #pragma unroll
    for (int i = 0; i < 13; i++) {
        int n = sub + 4 * i;
        gn[i] = (n < NV) ? key[n] : 0.0f;
        cnt[i] = 0;
    }
    for (int m = 0; m < NV; m++) {
        float gm = key[m];
        #pragma unroll
        for (int i = 0; i < 13; i++) {
            int n = sub + 4 * i;
            if (n < NV) {
                // rank(n) = #{m: g[m] > g[n]} + #{m < n: g[m] == g[n]} (stable argsort)
                cnt[i] += (gm > gn[i]) ? 1 : 0;
                if (m < n) cnt[i] += (gm == gn[i]) ? 1 : 0;
            }
        }
    }
    float tail = 0.0f;
    #pragma unroll
    for (int i = 0; i < 13; i++) {
        int n = sub + 4 * i;
        if (n < NV) {
            tail += ((float)cnt[i] > yval) ? mycl[n] : 0.0f;
        }
    }
    float contrib = tail * (49.0f / (49.0f - yval));

    // block reduce + one double atomic
    #pragma unroll
    for (int off = 32; off > 0; off >>= 1)
        contrib += __shfl_down(contrib, off);
    int lane = tid & 63, wid = tid >> 6;
    if (lane == 0) sred[wid] = contrib;
    __syncthreads();
    if (tid == 0)
        atomicAdd(acc + 0, (double)(sred[0] + sred[1] + sred[2] + sred[3]));
}

// ---------------------------------------------------------------------------
// Kernel C: combine -> scalar output
// ---------------------------------------------------------------------------
__global__ void finalize_kernel(const double* __restrict__ acc,
                                float* __restrict__ out)
{
    // cl mean over 4*49*240*240 ; lx/ly means over 4*240*239 each
    double cl = acc[0] / 11289600.0;
    double gl = (acc[1] + acc[2]) / (2.0 * 229440.0);
    out[0] = (float)(cl + 0.1 * gl);
}

extern "C" void kernel_launch(void* const* d_in, const int* in_sizes, int n_in,
                              void* d_out, int out_size, void* d_ws, size_t ws_size,
                              hipStream_t stream)
{
    const float* pred  = (const float*)d_in[0];
    const float* x     = (const float*)d_in[1];
    const float* y     = (const float*)d_in[2];
    const int*   epoch = (const int*)d_in[3];
    double* acc = (double*)d_ws;

    hipMemsetAsync(acc, 0, 3 * sizeof(double), stream);
    grad_kernel<<<NPIX / 256, 256, 0, stream>>>(pred, x, acc);
    color_kernel<<<NPIX / 64, 256, 0, stream>>>(pred, x, y, epoch, acc);
    finalize_kernel<<<1, 1, 0, stream>>>(acc, (float*)d_out);
}

// Round 2
// 325.531 us; speedup vs baseline: 1.0817x; 1.0817x over previous
//
#include <hip/hip_runtime.h>
#include <math.h>

#define NV    49
#define Himg  256
#define Wimg  256
#define RW    240
#define RWH   (RW*RW)          // 57600
#define NPIX  (4*RWH)          // 230400
#define ROWF  (Wimg*3)         // 768 floats per image row
#define IMGF  (Himg*Wimg*3)    // 196608 floats per view image
#define NBLK  (NPIX/64)        // 3600 blocks

// ---------------------------------------------------------------------------
// Fused kernel: warp-all + color loss + angular gauss + stable-rank tail sum
// + edge-aware smoothness (on the sub==3 wave, which carries only 7 views).
// 64 pixels/block, 4 sub-threads (waves) per pixel.
// ---------------------------------------------------------------------------

#define CL7(a) ((a)<0?0:((a)>6?6:(a)))

// bilinear sample of view (UC,VC) using precomputed separable interpolants
#define DO_VIEW(UC, VC) { \
    const float* s0p = xv + ((UC)*7 + (VC)) * IMGF + ro0 + co[VC]; \
    const float* s1p = xv + ((UC)*7 + (VC)) * IMGF + ro1 + co[VC]; \
    float s0[6], s1[6]; \
    __builtin_memcpy(s0, s0p, 24); \
    __builtin_memcpy(s1, s1p, 24); \
    float tx = txv[VC]; \
    float h0 = s0[0] + tx*(s0[3]-s0[0]); \
    float h1 = s0[1] + tx*(s0[4]-s0[1]); \
    float h2 = s0[2] + tx*(s0[5]-s0[2]); \
    float k0 = s1[0] + tx*(s1[3]-s1[0]); \
    float k1 = s1[1] + tx*(s1[4]-s1[1]); \
    float k2 = s1[2] + tx*(s1[5]-s1[2]); \
    float o0 = h0 + ty*(k0-h0); \
    float o1 = h1 + ty*(k1-h1); \
    float o2 = h2 + ty*(k2-h2); \
    mycl[(UC)*7+(VC)] = (fabsf(o0-c0)+fabsf(o1-c1)+fabsf(o2-c2)) * (1.0f/3.0f); \
}

#define DO_U(UC) { \
    float cy = fminf(fmaxf((float)yy + p * (float)((UC)-3), 0.0f), 255.0f); \
    float y0f = floorf(cy); \
    float ty = cy - y0f; \
    int iy0 = (int)y0f; \
    int iy1 = min(iy0+1, 255); \
    int ro0 = iy0*ROWF, ro1 = iy1*ROWF; \
    DO_VIEW(UC,0) DO_VIEW(UC,1) DO_VIEW(UC,2) DO_VIEW(UC,3) \
    DO_VIEW(UC,4) DO_VIEW(UC,5) DO_VIEW(UC,6) \
}

// 3x3 edge-padded gaussian over the 7x7 angular grid (all-static offsets)
#define GV(UC,VC) myg[(UC)*7+(VC)] = \
    0.0751f*mycl[CL7((UC)-1)*7+CL7((VC)-1)] + 0.1238f*mycl[CL7((UC)-1)*7+(VC)] + 0.0751f*mycl[CL7((UC)-1)*7+CL7((VC)+1)] + \
    0.1238f*mycl[(UC)*7+CL7((VC)-1)]        + 0.2042f*mycl[(UC)*7+(VC)]        + 0.1238f*mycl[(UC)*7+CL7((VC)+1)] + \
    0.0751f*mycl[CL7((UC)+1)*7+CL7((VC)-1)] + 0.1238f*mycl[CL7((UC)+1)*7+(VC)] + 0.0751f*mycl[CL7((UC)+1)*7+CL7((VC)+1)];

#define GU(UC) GV(UC,0) GV(UC,1) GV(UC,2) GV(UC,3) GV(UC,4) GV(UC,5) GV(UC,6)

__global__ __launch_bounds__(256) void color_kernel(
    const float* __restrict__ pred, const float* __restrict__ x,
    const float* __restrict__ y, const int* __restrict__ epoch_p,
    double* __restrict__ acc)
{
    __shared__ float s_cl[64 * NV];
    __shared__ float s_g [64 * NV];
    __shared__ float sred[4];

    const int tid = threadIdx.x;
    const int pix = tid & 63;
    const int sub = tid >> 6;          // wave id: wave-uniform

    // XCD band swizzle: XCD k (= bid%8) gets a contiguous 450-block band
    int lb  = (blockIdx.x & 7) * (NBLK/8) + (blockIdx.x >> 3);
    int pid = lb * 64 + pix;
    int b   = pid / RWH;
    int rem = pid - b * RWH;
    int ry  = rem / RW;
    int yy  = 8 + ry;
    int xx  = 8 + (rem - ry * RW);

    int pidx = (b * Himg + yy) * Wimg + xx;
    float p = pred[pidx];

    const float* xv    = x + (size_t)b * (49 * IMGF);
    const float* cbase = xv + (24 * IMGF) + (yy * Wimg + xx) * 3;
    float c0 = cbase[0], c1 = cbase[1], c2 = cbase[2];

    float* mycl = s_cl + pix * NV;
    float* myg  = s_g  + pix * NV;

    // separable x-interpolants (7), registers after full unroll
    int co[7]; float txv[7];
    #pragma unroll
    for (int vv = 0; vv < 7; vv++) {
        float cx = fminf(fmaxf((float)xx + p * (float)(vv-3), 0.0f), 255.0f);
        float x0f = floorf(cx);
        float tx = cx - x0f;
        int ix0 = (int)x0f;
        if (ix0 >= 255) { ix0 = 254; tx = 1.0f; }  // same bilinear result
        co[vv] = ix0 * 3; txv[vv] = tx;
    }

    // ---- stage 1 (wave-uniform branch; sub3 also does grad_loss) ----
    if (sub == 0)      { DO_U(0) DO_U(4) }
    else if (sub == 1) { DO_U(1) DO_U(5) }
    else if (sub == 2) { DO_U(2) DO_U(6) }
    else {
        DO_U(3)
        float lx = 0.0f, ly = 0.0f;
        if (xx <= 246) {
            float q6[6]; __builtin_memcpy(q6, cbase, 24);
            float wx = __expf(-50.0f * (fabsf(q6[3]-c0) + fabsf(q6[4]-c1) + fabsf(q6[5]-c2)));
            lx = wx * fabsf(pred[pidx + 1] - p);
        }
        if (yy <= 246) {
            float r0 = cbase[ROWF], r1 = cbase[ROWF+1], r2 = cbase[ROWF+2];
            float wy = __expf(-50.0f * (fabsf(r0-c0) + fabsf(r1-c1) + fabsf(r2-c2)));
            ly = wy * fabsf(pred[pidx + Wimg] - p);
        }
        #pragma unroll
        for (int off = 32; off > 0; off >>= 1) {
            lx += __shfl_down(lx, off);
            ly += __shfl_down(ly, off);
        }
        if ((tid & 63) == 0) {
            atomicAdd(acc + 1, (double)lx);
            atomicAdd(acc + 2, (double)ly);
        }
    }
    __syncthreads();

    const int epoch = *epoch_p;

    // ---- stage 2: angular gaussian (wave-uniform) ----
    if (epoch > 0) {
        if (sub == 0)      { GU(0) GU(4) }
        else if (sub == 1) { GU(1) GU(5) }
        else if (sub == 2) { GU(2) GU(6) }
        else               { GU(3) }
    }
    __syncthreads();

    // ---- stage 3: stable-descending rank via packed u64 keys ----
    const float* key = (epoch > 0) ? myg : mycl;
    float yval = y[pidx];

    unsigned long long kn[13];
    int cnt[13];
    #pragma unroll
    for (int i = 0; i < 13; i++) {
        int n = sub + 4*i;
        if (n < NV) {
            unsigned int bb = __float_as_uint(key[n]);   // key >= 0 -> bits ordered
            kn[i] = (((unsigned long long)bb) << 8) | (unsigned long long)(255 - n);
        } else kn[i] = ~0ULL;
        cnt[i] = 0;
    }
    for (int m = 0; m < NV; m++) {
        unsigned int bm = __float_as_uint(key[m]);
        unsigned long long km = (((unsigned long long)bm) << 8) | (unsigned long long)(255 - m);
        #pragma unroll
        for (int i = 0; i < 13; i++)
            cnt[i] += (km > kn[i]) ? 1 : 0;
    }
    float tail = 0.0f;
    #pragma unroll
    for (int i = 0; i < 13; i++) {
        int n = sub + 4*i;
        if (n < NV)
            tail += ((float)cnt[i] > yval) ? mycl[n] : 0.0f;
    }
    float contrib = tail * (49.0f / (49.0f - yval));

    #pragma unroll
    for (int off = 32; off > 0; off >>= 1)
        contrib += __shfl_down(contrib, off);
    if ((tid & 63) == 0) sred[sub] = contrib;
    __syncthreads();
    if (tid == 0)
        atomicAdd(acc + 0, (double)(sred[0] + sred[1] + sred[2] + sred[3]));
}

__global__ void finalize_kernel(const double* __restrict__ acc,
                                float* __restrict__ out)
{
    double cl = acc[0] / 11289600.0;           // 4*49*240*240
    double gl = (acc[1] + acc[2]) / (2.0 * 229440.0);  // 4*240*239 each
    out[0] = (float)(cl + 0.1 * gl);
}

extern "C" void kernel_launch(void* const* d_in, const int* in_sizes, int n_in,
                              void* d_out, int out_size, void* d_ws, size_t ws_size,
                              hipStream_t stream)
{
    const float* pred  = (const float*)d_in[0];
    const float* x     = (const float*)d_in[1];
    const float* y     = (const float*)d_in[2];
    const int*   epoch = (const int*)d_in[3];
    double* acc = (double*)d_ws;

    hipMemsetAsync(acc, 0, 3 * sizeof(double), stream);
    color_kernel<<<NBLK, 256, 0, stream>>>(pred, x, y, epoch, acc);
    finalize_kernel<<<1, 1, 0, stream>>>(acc, (float*)d_out);
}